// Round 2
// baseline (284.304 us; speedup 1.0000x reference)
//
#include <hip/hip_runtime.h>
#include <hip/hip_bf16.h>

typedef __attribute__((ext_vector_type(8))) short short8;
typedef __attribute__((ext_vector_type(4))) float f32x4;

union U8 {
  short8 v;
  unsigned long long q[2];
  unsigned int w[4];
};

__device__ __forceinline__ unsigned short f2bf(float x) {
  union { __hip_bfloat16 b; unsigned short u; } c;
  c.b = __float2bfloat16(x);
  return c.u;
}
__device__ __forceinline__ float bf2f(unsigned short u) {
  union { __hip_bfloat16 b; unsigned short u; } c;
  c.u = u;
  return __bfloat162float(c.b);
}
__device__ __forceinline__ unsigned int pk2(float lo, float hi) {
  return (unsigned int)f2bf(lo) | ((unsigned int)f2bf(hi) << 16);
}
// split x into hi (bf16) and lo (bf16 of residual)
__device__ __forceinline__ void splitbf(float x, unsigned short& hi, unsigned short& lo) {
  hi = f2bf(x);
  lo = f2bf(x - bf2f(hi));
}

constexpr int S_LEN = 2048;
constexpr int D_DIM = 64;
constexpr int BH    = 64;     // 4 batches * 16 heads
constexpr int KVB   = 64;     // kv tile rows
constexpr int SK    = 68;     // LDS row stride in bf16 elems (136 B): pads bank conflicts away
constexpr float LOG2E = 1.4426950408889634f;
constexpr float INV_D_QTR = 0.35355339059327373f;  // 1 / 64^0.25

__global__ __launch_bounds__(256) void attn_fwd(
    const float* __restrict__ Q, const float* __restrict__ K,
    const float* __restrict__ V, float* __restrict__ O)
{
  const int tid  = threadIdx.x;
  const int w    = tid >> 6;      // wave 0..3
  const int lane = tid & 63;
  const int m    = lane & 15;     // q-row within wave tile (and n/m index of MFMA frags)
  const int g    = lane >> 4;     // 4-lane-group index 0..3

  const int bh = blockIdx.y;
  const int q0 = blockIdx.x * 64; // block q base
  const int qw = q0 + w * 16;     // wave q base

  __shared__ unsigned short Ksh[64 * SK];  // K tile hi, [kv][d] bf16
  __shared__ unsigned short Ksl[64 * SK];  // K tile lo (residual), [kv][d] bf16
  __shared__ unsigned short Vt[64 * SK];   // V tile transposed, [d][kv] bf16

  const size_t base = (size_t)bh * S_LEN * D_DIM;

  // ---- Q fragments, split precision (B-operand of swapped QK^T) ----
  U8 qh[2], ql[2];
  {
    const float* qp = Q + base + (size_t)(qw + m) * D_DIM + g * 8;
    #pragma unroll
    for (int ko = 0; ko < 2; ++ko) {
      float x[8];
      *(float4*)&x[0] = *(const float4*)(qp + ko * 32);
      *(float4*)&x[4] = *(const float4*)(qp + ko * 32 + 4);
      #pragma unroll
      for (int j = 0; j < 4; ++j) {
        unsigned short h0, l0, h1, l1;
        splitbf(x[2 * j], h0, l0);
        splitbf(x[2 * j + 1], h1, l1);
        qh[ko].w[j] = (unsigned int)h0 | ((unsigned int)h1 << 16);
        ql[ko].w[j] = (unsigned int)l0 | ((unsigned int)l1 << 16);
      }
    }
  }

  f32x4 ot[4];   // O^T accum: ot[ds] holds O[q = lane&15][d = ds*16 + g*4 + r]
  #pragma unroll
  for (int ds = 0; ds < 4; ++ds) {
    f32x4 z = {0.f, 0.f, 0.f, 0.f};
    ot[ds] = z;
  }
  float mrow = -1e30f;  // running max for q-row (lane&15), replicated over g
  float lrow = 0.f;     // running denom

  for (int t = 0; t < S_LEN / KVB; ++t) {
    const int kv0 = t * KVB;

    // ---- stage K tile -> Ksh/Ksl bf16 hi/lo (coalesced float4 reads, b64 writes) ----
    #pragma unroll
    for (int p = 0; p < 2; ++p) {
      const int idx = p * 256 + tid;       // 0..511 over 64 rows x 8 chunks
      const int row = idx >> 3, c = idx & 7;
      const float* kp = K + base + (size_t)(kv0 + row) * D_DIM + c * 8;
      float x[8];
      *(float4*)&x[0] = *(const float4*)kp;
      *(float4*)&x[4] = *(const float4*)(kp + 4);
      unsigned int wh[4], wl[4];
      #pragma unroll
      for (int j = 0; j < 4; ++j) {
        unsigned short h0, l0, h1, l1;
        splitbf(x[2 * j], h0, l0);
        splitbf(x[2 * j + 1], h1, l1);
        wh[j] = (unsigned int)h0 | ((unsigned int)h1 << 16);
        wl[j] = (unsigned int)l0 | ((unsigned int)l1 << 16);
      }
      *(unsigned long long*)&Ksh[row * SK + c * 8] =
          (unsigned long long)wh[0] | ((unsigned long long)wh[1] << 32);
      *(unsigned long long*)&Ksh[row * SK + c * 8 + 4] =
          (unsigned long long)wh[2] | ((unsigned long long)wh[3] << 32);
      *(unsigned long long*)&Ksl[row * SK + c * 8] =
          (unsigned long long)wl[0] | ((unsigned long long)wl[1] << 32);
      *(unsigned long long*)&Ksl[row * SK + c * 8 + 4] =
          (unsigned long long)wl[2] | ((unsigned long long)wl[3] << 32);
    }
    // ---- stage V transposed -> Vt[d][kv] (coalesced dword reads, packed u32 writes) ----
    #pragma unroll
    for (int p = 0; p < 8; ++p) {
      const int kvp = w * 16 + p * 2;      // this wave's kv row pair
      const float* vp = V + base + (size_t)(kv0 + kvp) * D_DIM + lane;
      float a = vp[0];
      float b = vp[D_DIM];
      *(unsigned int*)&Vt[lane * SK + kvp] = pk2(a, b);
    }
    __syncthreads();

    // ---- swapped QK^T, split precision: S ~= Kh*Qh + Kh*Ql + Kl*Qh ----
    f32x4 sv[4];
    #pragma unroll
    for (int ks = 0; ks < 4; ++ks) {
      f32x4 acc = {0.f, 0.f, 0.f, 0.f};
      #pragma unroll
      for (int ko = 0; ko < 2; ++ko) {
        U8 ah, al;
        const int off = (ks * 16 + m) * SK + ko * 32 + g * 8;
        ah.q[0] = *(const unsigned long long*)&Ksh[off];
        ah.q[1] = *(const unsigned long long*)&Ksh[off + 4];
        al.q[0] = *(const unsigned long long*)&Ksl[off];
        al.q[1] = *(const unsigned long long*)&Ksl[off + 4];
        acc = __builtin_amdgcn_mfma_f32_16x16x32_bf16(ah.v, qh[ko].v, acc, 0, 0, 0);
        acc = __builtin_amdgcn_mfma_f32_16x16x32_bf16(ah.v, ql[ko].v, acc, 0, 0, 0);
        acc = __builtin_amdgcn_mfma_f32_16x16x32_bf16(al.v, qh[ko].v, acc, 0, 0, 0);
      }
      sv[ks] = acc;
    }

    // ---- online softmax (row q = lane&15 lives in lanes {q, q+16, q+32, q+48}) ----
    float pm = -1e30f;
    #pragma unroll
    for (int ks = 0; ks < 4; ++ks) {
      pm = fmaxf(pm, fmaxf(fmaxf(sv[ks][0], sv[ks][1]), fmaxf(sv[ks][2], sv[ks][3])));
    }
    pm = fmaxf(pm, __shfl_xor(pm, 16, 64));
    pm = fmaxf(pm, __shfl_xor(pm, 32, 64));
    const float mnew = fmaxf(mrow, pm);
    const float corr = exp2f((mrow - mnew) * LOG2E);
    float ps = 0.f;
    #pragma unroll
    for (int ks = 0; ks < 4; ++ks) {
      #pragma unroll
      for (int r = 0; r < 4; ++r) {
        const float p = exp2f((sv[ks][r] - mnew) * LOG2E);
        sv[ks][r] = p;
        ps += p;
      }
    }
    ps += __shfl_xor(ps, 16, 64);
    ps += __shfl_xor(ps, 32, 64);
    lrow = lrow * corr + ps;
    mrow = mnew;
    #pragma unroll
    for (int ds = 0; ds < 4; ++ds) {
      ot[ds][0] *= corr; ot[ds][1] *= corr;
      ot[ds][2] *= corr; ot[ds][3] *= corr;
    }

    // ---- swapped PV: O^T += V^T x P^T ----
    #pragma unroll
    for (int kk = 0; kk < 2; ++kk) {
      // pack own P contributions for both 16-kv subtiles of this 32-kv chunk
      const unsigned int a0 = pk2(sv[2 * kk][0], sv[2 * kk][1]);
      const unsigned int a1 = pk2(sv[2 * kk][2], sv[2 * kk][3]);
      const unsigned int b0 = pk2(sv[2 * kk + 1][0], sv[2 * kk + 1][1]);
      const unsigned int b1 = pk2(sv[2 * kk + 1][2], sv[2 * kk + 1][3]);
      const int srcA = m + ((lane & 16) << 1);   // q + 32*(g&1): sender group 2*(g&1)
      const int srcB = srcA + 16;                // sender group 2*(g&1)+1
      const unsigned int lo0 = (unsigned int)__shfl((int)a0, srcA, 64);
      const unsigned int lo1 = (unsigned int)__shfl((int)a1, srcA, 64);
      const unsigned int lo2 = (unsigned int)__shfl((int)a0, srcB, 64);
      const unsigned int lo3 = (unsigned int)__shfl((int)a1, srcB, 64);
      const unsigned int hi0 = (unsigned int)__shfl((int)b0, srcA, 64);
      const unsigned int hi1 = (unsigned int)__shfl((int)b1, srcA, 64);
      const unsigned int hi2 = (unsigned int)__shfl((int)b0, srcB, 64);
      const unsigned int hi3 = (unsigned int)__shfl((int)b1, srcB, 64);
      const bool up = (g >> 1) != 0;             // which 16-kv subtile this group consumes
      U8 pf;
      pf.w[0] = up ? hi0 : lo0;
      pf.w[1] = up ? hi1 : lo1;
      pf.w[2] = up ? hi2 : lo2;
      pf.w[3] = up ? hi3 : lo3;
      #pragma unroll
      for (int ds = 0; ds < 4; ++ds) {
        U8 vf;
        const int off = (ds * 16 + m) * SK + kk * 32 + g * 8;
        vf.q[0] = *(const unsigned long long*)&Vt[off];
        vf.q[1] = *(const unsigned long long*)&Vt[off + 4];
        ot[ds] = __builtin_amdgcn_mfma_f32_16x16x32_bf16(vf.v, pf.v, ot[ds], 0, 0, 0);
      }
    }
    __syncthreads();
  }

  // ---- epilogue: out = O^T-acc * (dim^-0.25 / l), coalesced float4 stores ----
  const float inv = INV_D_QTR / lrow;
  #pragma unroll
  for (int ds = 0; ds < 4; ++ds) {
    f32x4 o = ot[ds] * inv;
    float* op = O + base + (size_t)(qw + m) * D_DIM + ds * 16 + g * 4;
    *(f32x4*)op = o;
  }
}

extern "C" void kernel_launch(void* const* d_in, const int* in_sizes, int n_in,
                              void* d_out, int out_size, void* d_ws, size_t ws_size,
                              hipStream_t stream) {
  const float* q = (const float*)d_in[0];
  const float* k = (const float*)d_in[1];
  const float* v = (const float*)d_in[2];
  float* o = (float*)d_out;
  dim3 grid(S_LEN / 64, BH);
  attn_fwd<<<grid, dim3(256), 0, stream>>>(q, k, v, o);
}